// Round 1
// baseline (430.405 us; speedup 1.0000x reference)
//
#include <hip/hip_runtime.h>
#include <hip/hip_bf16.h>
#include <cstdio>

typedef __bf16 bf16_t;
typedef __attribute__((ext_vector_type(8))) __bf16 bf16x8;
typedef __attribute__((ext_vector_type(4))) __bf16 bf16x4;
typedef __attribute__((ext_vector_type(4))) float f32x4;

#define SCALE 0.17677669529663687f   // 32^-0.5
#define NWIN 294                     // 6*7*7
#define NB 256                       // 16*16 windows
#define MROWS 75264                  // 256*294

__device__ __forceinline__ void gload16(const void* g, void* l) {
  __builtin_amdgcn_global_load_lds(
      (const __attribute__((address_space(1))) void*)g,
      (__attribute__((address_space(3))) void*)l, 16, 0, 0);
}

// ---------------- K0a: convert weights to bf16 ----------------
__global__ void cvt_weights(const float* __restrict__ wq, const float* __restrict__ wo,
                            bf16_t* __restrict__ wqb, bf16_t* __restrict__ wob) {
  int t = blockIdx.x * 256 + threadIdx.x;   // 65536 threads total
  const int nq4 = 768 * 256 / 4;            // 49152
  if (t < nq4) {
    float4 v = ((const float4*)wq)[t];
    bf16x4 h = {(bf16_t)v.x, (bf16_t)v.y, (bf16_t)v.z, (bf16_t)v.w};
    ((bf16x4*)wqb)[t] = h;
  } else {
    int t2 = t - nq4;                       // < 16384
    float4 v = ((const float4*)wo)[t2];
    bf16x4 h = {(bf16_t)v.x, (bf16_t)v.y, (bf16_t)v.z, (bf16_t)v.w};
    ((bf16x4*)wob)[t2] = h;
  }
}

// ---------------- K0b: bias_full[h][i][j] = bias_table[rel_idx[i][j]][h], j-padded to 304 ----------------
__global__ void bias_kernel(const float* __restrict__ bt, const int* __restrict__ ridx,
                            bf16_t* __restrict__ biasf) {
  int t = blockIdx.x * 256 + threadIdx.x;
  if (t >= 8 * 294 * 304) return;
  int j = t % 304;
  int rest = t / 304;
  int i = rest % 294;
  int hh = rest / 294;
  float v = 0.f;
  if (j < 294) v = bt[ridx[i * 294 + j] * 8 + hh];
  biasf[t] = (bf16_t)v;
}

// ---------------- K1: QKV GEMM  qkv[R][j] = sum_k x_perm[R][k] * w_qkv[j][k] ----------------
// A: fp32 x with fused window permutation, reg-staged + cvt to bf16.  B: bf16 w_qkv via global_load_lds.
__global__ __launch_bounds__(256, 2)
void qkv_gemm(const float* __restrict__ x, const bf16_t* __restrict__ wqb,
              bf16_t* __restrict__ qkv) {
  __shared__ bf16_t As[2][128][64];
  __shared__ bf16_t Bs[2][128][64];
  const int tid = threadIdx.x;
  const int lane = tid & 63;
  const int w = tid >> 6;
  const int mt = blockIdx.x / 6, nt = blockIdx.x % 6;
  const int m0 = mt * 128, n0 = nt * 128;
  const int rsub = tid >> 4, csub = (tid & 15) * 4;

  // Per-thread A source pointers: row i*16+rsub of the M-tile, fused permutation.
  const float* asrc[8];
#pragma unroll
  for (int i = 0; i < 8; ++i) {
    int R = m0 + i * 16 + rsub;               // global xw row = b*294 + n
    int b_ = R / 294, n = R - b_ * 294;
    int l = n / 49, p = n - l * 49;
    int X = b_ >> 4, Y = b_ & 15;
    int srow = ((l * 16 + X) * 16 + Y) * 49 + p;
    asrc[i] = x + (size_t)srow * 256 + csub;
  }

  const f32x4 zero4 = {0.f, 0.f, 0.f, 0.f};
  f32x4 acc[4][4];
#pragma unroll
  for (int i = 0; i < 4; ++i)
#pragma unroll
    for (int j = 0; j < 4; ++j) acc[i][j] = zero4;

  auto stageA = [&](int buf, int kk) {
    const int k0 = kk * 64;
#pragma unroll
    for (int i = 0; i < 8; ++i) {
      float4 v = *(const float4*)(asrc[i] + k0);
      bf16x4 h = {(bf16_t)v.x, (bf16_t)v.y, (bf16_t)v.z, (bf16_t)v.w};
      *(bf16x4*)&As[buf][i * 16 + rsub][csub] = h;
    }
  };
  auto stageB = [&](int buf, int kk) {
    const int k0 = kk * 64;
#pragma unroll
    for (int i = 0; i < 4; ++i) {
      int row = w * 32 + i * 8;
      const bf16_t* g = wqb + (size_t)(n0 + row + (lane >> 3)) * 256 + k0 + (lane & 7) * 8;
      gload16(g, &Bs[buf][row][0]);   // lds offset = lane*16 -> row-major [row][64]
    }
  };
  auto compute = [&](int buf) {
    const int mb = (w >> 1) * 64, nb = (w & 1) * 64;
#pragma unroll
    for (int ks = 0; ks < 2; ++ks) {
      bf16x8 a[4], bb[4];
#pragma unroll
      for (int i = 0; i < 4; ++i)
        a[i] = *(const bf16x8*)&As[buf][mb + i * 16 + (lane & 15)][ks * 32 + (lane >> 4) * 8];
#pragma unroll
      for (int i = 0; i < 4; ++i)
        bb[i] = *(const bf16x8*)&Bs[buf][nb + i * 16 + (lane & 15)][ks * 32 + (lane >> 4) * 8];
#pragma unroll
      for (int i = 0; i < 4; ++i)
#pragma unroll
        for (int j = 0; j < 4; ++j)
          acc[i][j] = __builtin_amdgcn_mfma_f32_16x16x32_bf16(a[i], bb[j], acc[i][j], 0, 0, 0);
    }
  };

  stageA(0, 0); stageB(0, 0);
  __syncthreads();
#pragma unroll
  for (int kk = 0; kk < 4; ++kk) {
    int cur = kk & 1;
    if (kk < 3) { stageA(cur ^ 1, kk + 1); stageB(cur ^ 1, kk + 1); }
    compute(cur);
    __syncthreads();
  }

  const int mb = (w >> 1) * 64, nb = (w & 1) * 64;
#pragma unroll
  for (int i = 0; i < 4; ++i)
#pragma unroll
    for (int r = 0; r < 4; ++r) {
      int row = m0 + mb + i * 16 + (lane >> 4) * 4 + r;
      size_t rb = (size_t)row * 768;
#pragma unroll
      for (int j = 0; j < 4; ++j) {
        int col = n0 + nb + j * 16 + (lane & 15);
        float sc = (col < 256) ? SCALE : 1.0f;    // fold q-scale here
        qkv[rb + col] = (bf16_t)(acc[i][j][r] * sc);
      }
    }
}

// ---------------- K2: attention per (window, head) ----------------
__global__ __launch_bounds__(256, 2)
void attn_kernel(const bf16_t* __restrict__ qkv, const bf16_t* __restrict__ biasf,
                 bf16_t* __restrict__ aout) {
  __shared__ bf16_t Ksm[304][32];      // K rows (padded, zeroed >=294), swizzle ((row&3)<<4)
  __shared__ bf16_t Vsm[32][320];      // V^T [dh][k] (k padded to 320, zeroed), swizzle ((dh&7)<<4)
  __shared__ bf16_t Psm[4][16][320];   // per-wave P strip, swizzle ((row&7)<<4)
  const int tid = threadIdx.x, lane = tid & 63, w = tid >> 6;
  const int b_ = blockIdx.x >> 3, hh = blockIdx.x & 7;
  const size_t qbase = (size_t)b_ * 294 * 768;
  char* Kb = (char*)&Ksm[0][0];
  char* Vb = (char*)&Vsm[0][0];
  char* Pb = (char*)&Psm[w][0][0];

  // stage K (zero pad rows 294..303)
  for (int idx = tid; idx < 304 * 4; idx += 256) {
    int row = idx >> 2, qt = idx & 3;
    uint4 val = {0u, 0u, 0u, 0u};
    if (row < 294) val = *(const uint4*)(qkv + qbase + (size_t)row * 768 + 256 + hh * 32 + qt * 8);
    *(uint4*)(Kb + row * 64 + ((qt * 16) ^ ((row & 3) << 4))) = val;
  }
  // stage V transposed (scatter bf16)
  for (int idx = tid; idx < 294 * 4; idx += 256) {
    int row = idx >> 2, qt = idx & 3;
    uint4 val = *(const uint4*)(qkv + qbase + (size_t)row * 768 + 512 + hh * 32 + qt * 8);
    const unsigned short* pv = (const unsigned short*)&val;
#pragma unroll
    for (int e = 0; e < 8; ++e) {
      int j = qt * 8 + e;
      *(unsigned short*)(Vb + j * 640 + ((row * 2) ^ ((j & 7) << 4))) = pv[e];
    }
  }
  // zero V pad k=294..319
  for (int idx = tid; idx < 32 * 26; idx += 256) {
    int j = idx / 26, k2 = 294 + idx % 26;
    *(unsigned short*)(Vb + j * 640 + ((k2 * 2) ^ ((j & 7) << 4))) = 0;
  }
  // zero own P pad cols 304..319 (never written in strip loop)
  for (int idx = lane; idx < 256; idx += 64) {
    int prow = idx >> 4, pcol = 304 + (idx & 15);
    *(unsigned short*)(Pb + prow * 640 + ((pcol * 2) ^ ((prow & 7) << 4))) = 0;
  }
  __syncthreads();

  const f32x4 zero4 = {0.f, 0.f, 0.f, 0.f};
  for (int s = w; s < 19; s += 4) {
    // Q fragment: rows s*16..s*16+15
    uint4 qv = {0u, 0u, 0u, 0u};
    int qrow = s * 16 + (lane & 15);
    if (qrow < 294) qv = *(const uint4*)(qkv + qbase + (size_t)qrow * 768 + hh * 32 + (lane >> 4) * 8);
    bf16x8 qf = __builtin_bit_cast(bf16x8, qv);

    // S = Q K^T  (19 col-tiles)
    f32x4 sacc[19];
#pragma unroll
    for (int j = 0; j < 19; ++j) {
      int krow = j * 16 + (lane & 15);
      bf16x8 kf = *(const bf16x8*)(Kb + krow * 64 + (((lane >> 4) * 16) ^ ((krow & 3) << 4)));
      sacc[j] = __builtin_amdgcn_mfma_f32_16x16x32_bf16(qf, kf, zero4, 0, 0, 0);
    }

    // bias + column mask
#pragma unroll
    for (int j = 0; j < 19; ++j)
#pragma unroll
      for (int r = 0; r < 4; ++r) {
        int row = s * 16 + (lane >> 4) * 4 + r;
        int col = j * 16 + (lane & 15);
        float sv = sacc[j][r];
        if (row < 294) sv += (float)biasf[((size_t)hh * 294 + row) * 304 + col];
        if (col >= 294) sv = -1e30f;
        sacc[j][r] = sv;
      }

    // row softmax (rows live in 16-lane groups)
    float mx[4], sm[4];
#pragma unroll
    for (int r = 0; r < 4; ++r) {
      float m = -1e30f;
#pragma unroll
      for (int j = 0; j < 19; ++j) m = fmaxf(m, sacc[j][r]);
#pragma unroll
      for (int d2 = 1; d2 < 16; d2 <<= 1) m = fmaxf(m, __shfl_xor(m, d2));
      mx[r] = m; sm[r] = 0.f;
    }
#pragma unroll
    for (int j = 0; j < 19; ++j)
#pragma unroll
      for (int r = 0; r < 4; ++r) {
        float p = __expf(sacc[j][r] - mx[r]);
        sacc[j][r] = p;
        sm[r] += p;
      }
#pragma unroll
    for (int r = 0; r < 4; ++r) {
      float ssum = sm[r];
#pragma unroll
      for (int d2 = 1; d2 < 16; d2 <<= 1) ssum += __shfl_xor(ssum, d2);
      sm[r] = 1.f / ssum;
    }
    // write P strip (bf16) to private LDS
#pragma unroll
    for (int j = 0; j < 19; ++j)
#pragma unroll
      for (int r = 0; r < 4; ++r) {
        int prow = (lane >> 4) * 4 + r, pcol = j * 16 + (lane & 15);
        *(bf16_t*)(Pb + prow * 640 + ((pcol * 2) ^ ((prow & 7) << 4))) =
            (bf16_t)(sacc[j][r] * sm[r]);
      }

    // O = P V  (K padded to 320; pads are zero on V side)
    f32x4 oacc[2] = {zero4, zero4};
#pragma unroll
    for (int ks = 0; ks < 10; ++ks) {
      int prow = lane & 15;
      bf16x8 pf = *(const bf16x8*)(Pb + prow * 640 +
                                   ((ks * 64 + (lane >> 4) * 16) ^ ((prow & 7) << 4)));
#pragma unroll
      for (int nt = 0; nt < 2; ++nt) {
        int vrow = nt * 16 + (lane & 15);
        bf16x8 vf = *(const bf16x8*)(Vb + vrow * 640 +
                                     ((ks * 64 + (lane >> 4) * 16) ^ ((vrow & 7) << 4)));
        oacc[nt] = __builtin_amdgcn_mfma_f32_16x16x32_bf16(pf, vf, oacc[nt], 0, 0, 0);
      }
    }
    // write O rows
#pragma unroll
    for (int nt = 0; nt < 2; ++nt)
#pragma unroll
      for (int r = 0; r < 4; ++r) {
        int row = s * 16 + (lane >> 4) * 4 + r;
        if (row < 294)
          aout[((size_t)b_ * 294 + row) * 256 + hh * 32 + nt * 16 + (lane & 15)] =
              (bf16_t)oacc[nt][r];
      }
  }
}

// ---------------- K3: output GEMM + inverse permutation, fp32 out ----------------
__global__ __launch_bounds__(256, 2)
void out_gemm(const bf16_t* __restrict__ aout, const bf16_t* __restrict__ wob,
              float* __restrict__ out) {
  __shared__ bf16_t As[2][128][64];
  __shared__ bf16_t Bs[2][128][64];
  const int tid = threadIdx.x, lane = tid & 63, w = tid >> 6;
  const int mt = blockIdx.x >> 1, nt = blockIdx.x & 1;
  const int m0 = mt * 128, n0 = nt * 128;

  const f32x4 zero4 = {0.f, 0.f, 0.f, 0.f};
  f32x4 acc[4][4];
#pragma unroll
  for (int i = 0; i < 4; ++i)
#pragma unroll
    for (int j = 0; j < 4; ++j) acc[i][j] = zero4;

  auto stage = [&](int buf, int kk) {
    const int k0 = kk * 64;
#pragma unroll
    for (int i = 0; i < 4; ++i) {
      int row = w * 32 + i * 8;
      gload16(aout + (size_t)(m0 + row + (lane >> 3)) * 256 + k0 + (lane & 7) * 8,
              &As[buf][row][0]);
      gload16(wob + (size_t)(n0 + row + (lane >> 3)) * 256 + k0 + (lane & 7) * 8,
              &Bs[buf][row][0]);
    }
  };
  auto compute = [&](int buf) {
    const int mb = (w >> 1) * 64, nb = (w & 1) * 64;
#pragma unroll
    for (int ks = 0; ks < 2; ++ks) {
      bf16x8 a[4], bb[4];
#pragma unroll
      for (int i = 0; i < 4; ++i)
        a[i] = *(const bf16x8*)&As[buf][mb + i * 16 + (lane & 15)][ks * 32 + (lane >> 4) * 8];
#pragma unroll
      for (int i = 0; i < 4; ++i)
        bb[i] = *(const bf16x8*)&Bs[buf][nb + i * 16 + (lane & 15)][ks * 32 + (lane >> 4) * 8];
#pragma unroll
      for (int i = 0; i < 4; ++i)
#pragma unroll
        for (int j = 0; j < 4; ++j)
          acc[i][j] = __builtin_amdgcn_mfma_f32_16x16x32_bf16(a[i], bb[j], acc[i][j], 0, 0, 0);
    }
  };

  stage(0, 0);
  __syncthreads();
#pragma unroll
  for (int kk = 0; kk < 4; ++kk) {
    int cur = kk & 1;
    if (kk < 3) stage(cur ^ 1, kk + 1);
    compute(cur);
    __syncthreads();
  }

  const int mb = (w >> 1) * 64, nb = (w & 1) * 64;
#pragma unroll
  for (int i = 0; i < 4; ++i)
#pragma unroll
    for (int r = 0; r < 4; ++r) {
      int R = m0 + mb + i * 16 + (lane >> 4) * 4 + r;   // window-order row b*294+n
      int b_ = R / 294, n = R - b_ * 294;
      int l = n / 49, p = n - l * 49;
      int X = b_ >> 4, Y = b_ & 15;
      size_t drow = (size_t)(((l * 16 + X) * 16 + Y) * 49 + p) * 256;
#pragma unroll
      for (int j = 0; j < 4; ++j) {
        int col = n0 + nb + j * 16 + (lane & 15);
        out[drow + col] = acc[i][j][r];
      }
    }
}

// ---------------- launch ----------------
extern "C" void kernel_launch(void* const* d_in, const int* in_sizes, int n_in,
                              void* d_out, int out_size, void* d_ws, size_t ws_size,
                              hipStream_t stream) {
  const float* x   = (const float*)d_in[0];
  const float* wq  = (const float*)d_in[1];
  const float* wo  = (const float*)d_in[2];
  const float* bt  = (const float*)d_in[3];
  const int*   ri  = (const int*)d_in[4];
  float* out = (float*)d_out;

  char* ws = (char*)d_ws;
  bf16_t* qkv   = (bf16_t*)(ws);                  // 115,605,504 B
  bf16_t* aoutp = (bf16_t*)(ws + 115605504);      //  38,535,168 B
  bf16_t* wqb   = (bf16_t*)(ws + 154140672);      //     393,216 B
  bf16_t* wob   = (bf16_t*)(ws + 154533888);      //     131,072 B
  bf16_t* biasf = (bf16_t*)(ws + 154664960);      //   1,430,016 B -> total 156,094,976
  if (ws_size < 156094976ULL)
    fprintf(stderr, "WS TOO SMALL: %zu < 156094976\n", ws_size);

  hipLaunchKernelGGL(cvt_weights, dim3(256), dim3(256), 0, stream, wq, wo, wqb, wob);
  hipLaunchKernelGGL(bias_kernel, dim3(2793), dim3(256), 0, stream, bt, ri, biasf);
  hipLaunchKernelGGL(qkv_gemm, dim3(588 * 6), dim3(256), 0, stream, x, wqb, qkv);
  hipLaunchKernelGGL(attn_kernel, dim3(2048), dim3(256), 0, stream, qkv, biasf, aoutp);
  hipLaunchKernelGGL(out_gemm, dim3(588 * 2), dim3(256), 0, stream, aoutp, wob, out);
}

// Round 2
// 268.986 us; speedup vs baseline: 1.6001x; 1.6001x over previous
//
#include <hip/hip_runtime.h>
#include <hip/hip_bf16.h>
#include <cstdio>

typedef __bf16 bf16_t;
typedef __attribute__((ext_vector_type(8))) __bf16 bf16x8;
typedef __attribute__((ext_vector_type(4))) __bf16 bf16x4;
typedef __attribute__((ext_vector_type(4))) float f32x4;

#define SCALE 0.17677669529663687f   // 32^-0.5
#define NWIN 294                     // 6*7*7
#define NB 256                       // 16*16 windows
#define MROWS 75264                  // 256*294

__device__ __forceinline__ void gload16(const void* g, void* l) {
  __builtin_amdgcn_global_load_lds(
      (const __attribute__((address_space(1))) void*)g,
      (__attribute__((address_space(3))) void*)l, 16, 0, 0);
}

// ---------------- K0a: convert weights to bf16 ----------------
__global__ void cvt_weights(const float* __restrict__ wq, const float* __restrict__ wo,
                            bf16_t* __restrict__ wqb, bf16_t* __restrict__ wob) {
  int t = blockIdx.x * 256 + threadIdx.x;   // 65536 threads total
  const int nq4 = 768 * 256 / 4;            // 49152
  if (t < nq4) {
    float4 v = ((const float4*)wq)[t];
    bf16x4 h = {(bf16_t)v.x, (bf16_t)v.y, (bf16_t)v.z, (bf16_t)v.w};
    ((bf16x4*)wqb)[t] = h;
  } else {
    int t2 = t - nq4;                       // < 16384
    float4 v = ((const float4*)wo)[t2];
    bf16x4 h = {(bf16_t)v.x, (bf16_t)v.y, (bf16_t)v.z, (bf16_t)v.w};
    ((bf16x4*)wob)[t2] = h;
  }
}

// ---------------- K0b: bias in MFMA C-fragment layout ----------------
// biasf[h][s][j][lane][r]  (s = 16-row strip, j = 16-col tile, 64 lanes, 4 regs)
// value = bias[row][col] with col>=294 mask folded as -1e30, row-pad as 0.
__global__ void bias_kernel(const float* __restrict__ bt, const int* __restrict__ ridx,
                            bf16_t* __restrict__ biasf) {
  int t = blockIdx.x * 256 + threadIdx.x;
  if (t >= 8 * 19 * 19 * 256) return;
  int r = t & 3, L = (t >> 2) & 63;
  int jj = t >> 8;
  int j = jj % 19; jj /= 19;
  int s = jj % 19; int hh = jj / 19;
  int row = s * 16 + ((L >> 4) << 2) + r;
  int col = j * 16 + (L & 15);
  float v;
  if (col >= 294)      v = -1e30f;
  else if (row >= 294) v = 0.f;
  else                 v = bt[ridx[row * 294 + col] * 8 + hh];
  biasf[t] = (bf16_t)v;
}

// ---------------- K1: QKV GEMM  qkv[R][j] = sum_k x_perm[R][k] * w_qkv[j][k] ----------------
__global__ __launch_bounds__(256, 2)
void qkv_gemm(const float* __restrict__ x, const bf16_t* __restrict__ wqb,
              bf16_t* __restrict__ qkv) {
  __shared__ bf16_t As[2][128][64];
  __shared__ bf16_t Bs[2][128][64];
  const int tid = threadIdx.x;
  const int lane = tid & 63;
  const int w = tid >> 6;
  const int mt = blockIdx.x / 6, nt = blockIdx.x % 6;
  const int m0 = mt * 128, n0 = nt * 128;
  const int rsub = tid >> 4, csub = (tid & 15) * 4;

  const float* asrc[8];
#pragma unroll
  for (int i = 0; i < 8; ++i) {
    int R = m0 + i * 16 + rsub;               // global xw row = b*294 + n
    int b_ = R / 294, n = R - b_ * 294;
    int l = n / 49, p = n - l * 49;
    int X = b_ >> 4, Y = b_ & 15;
    int srow = ((l * 16 + X) * 16 + Y) * 49 + p;
    asrc[i] = x + (size_t)srow * 256 + csub;
  }

  const f32x4 zero4 = {0.f, 0.f, 0.f, 0.f};
  f32x4 acc[4][4];
#pragma unroll
  for (int i = 0; i < 4; ++i)
#pragma unroll
    for (int j = 0; j < 4; ++j) acc[i][j] = zero4;

  auto stageA = [&](int buf, int kk) {
    const int k0 = kk * 64;
#pragma unroll
    for (int i = 0; i < 8; ++i) {
      float4 v = *(const float4*)(asrc[i] + k0);
      bf16x4 h = {(bf16_t)v.x, (bf16_t)v.y, (bf16_t)v.z, (bf16_t)v.w};
      *(bf16x4*)&As[buf][i * 16 + rsub][csub] = h;
    }
  };
  auto stageB = [&](int buf, int kk) {
    const int k0 = kk * 64;
#pragma unroll
    for (int i = 0; i < 4; ++i) {
      int row = w * 32 + i * 8;
      const bf16_t* g = wqb + (size_t)(n0 + row + (lane >> 3)) * 256 + k0 + (lane & 7) * 8;
      gload16(g, &Bs[buf][row][0]);
    }
  };
  auto compute = [&](int buf) {
    const int mb = (w >> 1) * 64, nb = (w & 1) * 64;
#pragma unroll
    for (int ks = 0; ks < 2; ++ks) {
      bf16x8 a[4], bb[4];
#pragma unroll
      for (int i = 0; i < 4; ++i)
        a[i] = *(const bf16x8*)&As[buf][mb + i * 16 + (lane & 15)][ks * 32 + (lane >> 4) * 8];
#pragma unroll
      for (int i = 0; i < 4; ++i)
        bb[i] = *(const bf16x8*)&Bs[buf][nb + i * 16 + (lane & 15)][ks * 32 + (lane >> 4) * 8];
#pragma unroll
      for (int i = 0; i < 4; ++i)
#pragma unroll
        for (int j = 0; j < 4; ++j)
          acc[i][j] = __builtin_amdgcn_mfma_f32_16x16x32_bf16(a[i], bb[j], acc[i][j], 0, 0, 0);
    }
  };

  stageA(0, 0); stageB(0, 0);
  __syncthreads();
#pragma unroll
  for (int kk = 0; kk < 4; ++kk) {
    int cur = kk & 1;
    if (kk < 3) { stageA(cur ^ 1, kk + 1); stageB(cur ^ 1, kk + 1); }
    compute(cur);
    __syncthreads();
  }

  const int mb = (w >> 1) * 64, nb = (w & 1) * 64;
#pragma unroll
  for (int i = 0; i < 4; ++i)
#pragma unroll
    for (int r = 0; r < 4; ++r) {
      int row = m0 + mb + i * 16 + (lane >> 4) * 4 + r;
      size_t rb = (size_t)row * 768;
#pragma unroll
      for (int j = 0; j < 4; ++j) {
        int col = n0 + nb + j * 16 + (lane & 15);
        float sc = (col < 256) ? SCALE : 1.0f;    // fold q-scale here
        qkv[rb + col] = (bf16_t)(acc[i][j][r] * sc);
      }
    }
}

// ---------------- K2: attention per (window, head) ----------------
__global__ __launch_bounds__(256, 2)
void attn_kernel(const bf16_t* __restrict__ qkv, const bf16_t* __restrict__ biasf,
                 bf16_t* __restrict__ aout) {
  __shared__ bf16_t Ksm[304][32];      // K rows (padded, zeroed >=294), swizzle ((row&3)<<4)
  __shared__ bf16_t Vsm[32][320];      // V^T [dh][k] (k padded to 320, zeroed), swizzle ((dh&7)<<4)
  __shared__ bf16_t Psm[4][16][320];   // per-wave P strip, swizzle ((row&7)<<4)
  const int tid = threadIdx.x, lane = tid & 63, w = tid >> 6;
  const int b_ = blockIdx.x >> 3, hh = blockIdx.x & 7;
  const size_t qbase = (size_t)b_ * 294 * 768;
  char* Kb = (char*)&Ksm[0][0];
  char* Vb = (char*)&Vsm[0][0];
  char* Pb = (char*)&Psm[w][0][0];

  // stage K (zero pad rows 294..303)
  for (int idx = tid; idx < 304 * 4; idx += 256) {
    int row = idx >> 2, qt = idx & 3;
    uint4 val = {0u, 0u, 0u, 0u};
    if (row < 294) val = *(const uint4*)(qkv + qbase + (size_t)row * 768 + 256 + hh * 32 + qt * 8);
    *(uint4*)(Kb + row * 64 + ((qt * 16) ^ ((row & 3) << 4))) = val;
  }
  // stage V transposed (scatter bf16)
  for (int idx = tid; idx < 294 * 4; idx += 256) {
    int row = idx >> 2, qt = idx & 3;
    uint4 val = *(const uint4*)(qkv + qbase + (size_t)row * 768 + 512 + hh * 32 + qt * 8);
    const unsigned short* pv = (const unsigned short*)&val;
#pragma unroll
    for (int e = 0; e < 8; ++e) {
      int j = qt * 8 + e;
      *(unsigned short*)(Vb + j * 640 + ((row * 2) ^ ((j & 7) << 4))) = pv[e];
    }
  }
  // zero V pad k=294..319
  for (int idx = tid; idx < 32 * 26; idx += 256) {
    int j = idx / 26, k2 = 294 + idx % 26;
    *(unsigned short*)(Vb + j * 640 + ((k2 * 2) ^ ((j & 7) << 4))) = 0;
  }
  // zero own P pad cols 304..319
  for (int idx = lane; idx < 256; idx += 64) {
    int prow = idx >> 4, pcol = 304 + (idx & 15);
    *(unsigned short*)(Pb + prow * 640 + ((pcol * 2) ^ ((prow & 7) << 4))) = 0;
  }
  __syncthreads();

  const f32x4 zero4 = {0.f, 0.f, 0.f, 0.f};
  for (int s = w; s < 19; s += 4) {
    // Q fragment: rows s*16..s*16+15
    uint4 qv = {0u, 0u, 0u, 0u};
    int qrow = s * 16 + (lane & 15);
    if (qrow < 294) qv = *(const uint4*)(qkv + qbase + (size_t)qrow * 768 + hh * 32 + (lane >> 4) * 8);
    bf16x8 qf = __builtin_bit_cast(bf16x8, qv);

    // S = Q K^T  (19 col-tiles)
    f32x4 sacc[19];
#pragma unroll
    for (int j = 0; j < 19; ++j) {
      int krow = j * 16 + (lane & 15);
      bf16x8 kf = *(const bf16x8*)(Kb + krow * 64 + (((lane >> 4) * 16) ^ ((krow & 3) << 4)));
      sacc[j] = __builtin_amdgcn_mfma_f32_16x16x32_bf16(qf, kf, zero4, 0, 0, 0);
    }

    // bias add — fragment-layout table, coalesced 8B per j, masks pre-folded
    {
      const bf16_t* bfr = biasf + (size_t)(((hh * 19 + s) * 19) << 8) + (lane << 2);
#pragma unroll
      for (int j = 0; j < 19; ++j) {
        bf16x4 bv = *(const bf16x4*)(bfr + (j << 8));
#pragma unroll
        for (int r = 0; r < 4; ++r) sacc[j][r] += (float)bv[r];
      }
    }

    // row softmax (rows live in 16-lane groups)
    float mx[4], sm[4];
#pragma unroll
    for (int r = 0; r < 4; ++r) {
      float m = -1e30f;
#pragma unroll
      for (int j = 0; j < 19; ++j) m = fmaxf(m, sacc[j][r]);
#pragma unroll
      for (int d2 = 1; d2 < 16; d2 <<= 1) m = fmaxf(m, __shfl_xor(m, d2));
      mx[r] = m; sm[r] = 0.f;
    }
#pragma unroll
    for (int j = 0; j < 19; ++j)
#pragma unroll
      for (int r = 0; r < 4; ++r) {
        float p = __expf(sacc[j][r] - mx[r]);
        sacc[j][r] = p;
        sm[r] += p;
      }
#pragma unroll
    for (int r = 0; r < 4; ++r) {
      float ssum = sm[r];
#pragma unroll
      for (int d2 = 1; d2 < 16; d2 <<= 1) ssum += __shfl_xor(ssum, d2);
      sm[r] = 1.f / ssum;
    }
    // write P strip (bf16) to private LDS
#pragma unroll
    for (int j = 0; j < 19; ++j)
#pragma unroll
      for (int r = 0; r < 4; ++r) {
        int prow = (lane >> 4) * 4 + r, pcol = j * 16 + (lane & 15);
        *(bf16_t*)(Pb + prow * 640 + ((pcol * 2) ^ ((prow & 7) << 4))) =
            (bf16_t)(sacc[j][r] * sm[r]);
      }

    // O = P V  (K padded to 320; pads are zero on V side)
    f32x4 oacc[2] = {zero4, zero4};
#pragma unroll
    for (int ks = 0; ks < 10; ++ks) {
      int prow = lane & 15;
      bf16x8 pf = *(const bf16x8*)(Pb + prow * 640 +
                                   ((ks * 64 + (lane >> 4) * 16) ^ ((prow & 7) << 4)));
#pragma unroll
      for (int nt = 0; nt < 2; ++nt) {
        int vrow = nt * 16 + (lane & 15);
        bf16x8 vf = *(const bf16x8*)(Vb + vrow * 640 +
                                     ((ks * 64 + (lane >> 4) * 16) ^ ((vrow & 7) << 4)));
        oacc[nt] = __builtin_amdgcn_mfma_f32_16x16x32_bf16(pf, vf, oacc[nt], 0, 0, 0);
      }
    }
    // write O rows
#pragma unroll
    for (int nt = 0; nt < 2; ++nt)
#pragma unroll
      for (int r = 0; r < 4; ++r) {
        int row = s * 16 + (lane >> 4) * 4 + r;
        if (row < 294)
          aout[((size_t)b_ * 294 + row) * 256 + hh * 32 + nt * 16 + (lane & 15)] =
              (bf16_t)oacc[nt][r];
      }
  }
}

// ---------------- K3: output GEMM + inverse permutation, fp32 out ----------------
__global__ __launch_bounds__(256, 2)
void out_gemm(const bf16_t* __restrict__ aout, const bf16_t* __restrict__ wob,
              float* __restrict__ out) {
  __shared__ bf16_t As[2][128][64];
  __shared__ bf16_t Bs[2][128][64];
  const int tid = threadIdx.x, lane = tid & 63, w = tid >> 6;
  const int mt = blockIdx.x >> 1, nt = blockIdx.x & 1;
  const int m0 = mt * 128, n0 = nt * 128;

  const f32x4 zero4 = {0.f, 0.f, 0.f, 0.f};
  f32x4 acc[4][4];
#pragma unroll
  for (int i = 0; i < 4; ++i)
#pragma unroll
    for (int j = 0; j < 4; ++j) acc[i][j] = zero4;

  auto stage = [&](int buf, int kk) {
    const int k0 = kk * 64;
#pragma unroll
    for (int i = 0; i < 4; ++i) {
      int row = w * 32 + i * 8;
      gload16(aout + (size_t)(m0 + row + (lane >> 3)) * 256 + k0 + (lane & 7) * 8,
              &As[buf][row][0]);
      gload16(wob + (size_t)(n0 + row + (lane >> 3)) * 256 + k0 + (lane & 7) * 8,
              &Bs[buf][row][0]);
    }
  };
  auto compute = [&](int buf) {
    const int mb = (w >> 1) * 64, nb = (w & 1) * 64;
#pragma unroll
    for (int ks = 0; ks < 2; ++ks) {
      bf16x8 a[4], bb[4];
#pragma unroll
      for (int i = 0; i < 4; ++i)
        a[i] = *(const bf16x8*)&As[buf][mb + i * 16 + (lane & 15)][ks * 32 + (lane >> 4) * 8];
#pragma unroll
      for (int i = 0; i < 4; ++i)
        bb[i] = *(const bf16x8*)&Bs[buf][nb + i * 16 + (lane & 15)][ks * 32 + (lane >> 4) * 8];
#pragma unroll
      for (int i = 0; i < 4; ++i)
#pragma unroll
        for (int j = 0; j < 4; ++j)
          acc[i][j] = __builtin_amdgcn_mfma_f32_16x16x32_bf16(a[i], bb[j], acc[i][j], 0, 0, 0);
    }
  };

  stage(0, 0);
  __syncthreads();
#pragma unroll
  for (int kk = 0; kk < 4; ++kk) {
    int cur = kk & 1;
    if (kk < 3) stage(cur ^ 1, kk + 1);
    compute(cur);
    __syncthreads();
  }

  const int mb = (w >> 1) * 64, nb = (w & 1) * 64;
#pragma unroll
  for (int i = 0; i < 4; ++i)
#pragma unroll
    for (int r = 0; r < 4; ++r) {
      int R = m0 + mb + i * 16 + (lane >> 4) * 4 + r;   // window-order row b*294+n
      int b_ = R / 294, n = R - b_ * 294;
      int l = n / 49, p = n - l * 49;
      int X = b_ >> 4, Y = b_ & 15;
      size_t drow = (size_t)(((l * 16 + X) * 16 + Y) * 49 + p) * 256;
#pragma unroll
      for (int j = 0; j < 4; ++j) {
        int col = n0 + nb + j * 16 + (lane & 15);
        out[drow + col] = acc[i][j][r];
      }
    }
}

// ---------------- launch ----------------
extern "C" void kernel_launch(void* const* d_in, const int* in_sizes, int n_in,
                              void* d_out, int out_size, void* d_ws, size_t ws_size,
                              hipStream_t stream) {
  const float* x   = (const float*)d_in[0];
  const float* wq  = (const float*)d_in[1];
  const float* wo  = (const float*)d_in[2];
  const float* bt  = (const float*)d_in[3];
  const int*   ri  = (const int*)d_in[4];
  float* out = (float*)d_out;

  char* ws = (char*)d_ws;
  bf16_t* qkv   = (bf16_t*)(ws);                  // 115,605,504 B
  bf16_t* aoutp = (bf16_t*)(ws + 115605504);      //  38,535,168 B
  bf16_t* wqb   = (bf16_t*)(ws + 154140672);      //     393,216 B
  bf16_t* wob   = (bf16_t*)(ws + 154533888);      //     131,072 B
  bf16_t* biasf = (bf16_t*)(ws + 154664960);      //   1,478,656 B -> total 156,143,616
  if (ws_size < 156143616ULL)
    fprintf(stderr, "WS TOO SMALL: %zu < 156143616\n", ws_size);

  hipLaunchKernelGGL(cvt_weights, dim3(256), dim3(256), 0, stream, wq, wo, wqb, wob);
  hipLaunchKernelGGL(bias_kernel, dim3(2888), dim3(256), 0, stream, bt, ri, biasf);
  hipLaunchKernelGGL(qkv_gemm, dim3(588 * 6), dim3(256), 0, stream, x, wqb, qkv);
  hipLaunchKernelGGL(attn_kernel, dim3(2048), dim3(256), 0, stream, qkv, biasf, aoutp);
  hipLaunchKernelGGL(out_gemm, dim3(588 * 2), dim3(256), 0, stream, aoutp, wob, out);
}